// Round 3
// baseline (127.520 us; speedup 1.0000x reference)
//
#include <hip/hip_runtime.h>

#define KTAPS 10
#define SKIP  2
#define TRANS 100
#define PAD   ((KTAPS - 1) * SKIP)   // 18
#define NFEAT 231                    // 1 + 10 + 220
#define NIN   4096
#define NT    (NIN - TRANS)          // 3996
#define NROWS 32                     // 8*4
#define TT    64                     // timesteps per block
#define NTHREADS 512                 // 8 waves

// Native clang vector: __builtin_nontemporal_store requires a real vector
// type (HIP's float4 is a class and is rejected).
typedef float f32x4 __attribute__((ext_vector_type(4)));

// Emit monomials for pair-index range [PLO,PHI) of the i<=j pairs (55 total),
// fully unrolled so every f-offset and tap index is a compile-time constant.
// Lex order matches itertools.combinations_with_replacement(range(10), 3).
template<int PLO, int PHI, bool LIN>
__device__ __forceinline__ void emit_features(const float* __restrict__ tap,
                                              float* __restrict__ frow) {
    if (LIN) {
        frow[0] = 1.0f;
#pragma unroll
        for (int k = 0; k < KTAPS; ++k) frow[1 + k] = tap[k];
    }
    int p = 0, fb = 1 + KTAPS;
#pragma unroll
    for (int i = 0; i < KTAPS; ++i) {
#pragma unroll
        for (int j = i; j < KTAPS; ++j) {
            if (p >= PLO && p < PHI) {           // folds: PLO/PHI/p all constants
                const float pij = tap[i] * tap[j];
#pragma unroll
                for (int l = j; l < KTAPS; ++l)
                    frow[fb + (l - j)] = pij * tap[l];
            }
            fb += KTAPS - j;
            ++p;
        }
    }
}

__global__ __launch_bounds__(NTHREADS, 4) void nvar_kernel(const float* __restrict__ X,
                                                           float* __restrict__ out) {
    // LDS tile laid out EXACTLY like the output slab: [t][feat], stride 231.
    // 231 % 32 = 7 (odd, coprime with 32) -> compute-phase writes (fixed f,
    // t = lane 0..63) hit each of the 32 banks exactly twice = free on wave64.
    // 64*231*4 = 59,136 B -> 2 blocks/CU (16 waves/CU).
    __shared__ float feat[TT * NFEAT];

    const int tile = blockIdx.x;
    const int row  = blockIdx.y;
    const int t0   = tile * TT;
    const int tcount = min(TT, NT - t0);         // 64, or 28 on the tail tile

    const int tl = threadIdx.x & 63;             // local timestep = full lane id
    const int wq = threadIdx.x >> 6;             // wave id 0..7, wave-uniform

    int tg = t0 + tl;
    if (tg >= NT) tg = NT - 1;                   // tail clamp; extra rows unused

    // lin_k(t) = X[row, t + 82 + 2k]; max index 3995+82+18 = 4095, in-bounds.
    const float* xrow = X + (size_t)row * NIN;
    float tap[KTAPS];
#pragma unroll
    for (int k = 0; k < KTAPS; ++k)
        tap[k] = xrow[tg + (TRANS - PAD) + 2 * k];

    // 8 wave-groups, each covering all 64 timesteps for a disjoint pair-range.
    // Balanced ds_write counts per wave: 30,26,27,28,30,31,29,30.
    float* frow = feat + tl * NFEAT;
    switch (wq) {
        case 0:  emit_features< 0,  2, true >(tap, frow); break;
        case 1:  emit_features< 2,  6, false>(tap, frow); break;
        case 2:  emit_features< 6, 12, false>(tap, frow); break;
        case 3:  emit_features<12, 19, false>(tap, frow); break;
        case 4:  emit_features<19, 24, false>(tap, frow); break;
        case 5:  emit_features<24, 32, false>(tap, frow); break;
        case 6:  emit_features<32, 41, false>(tap, frow); break;
        default: emit_features<41, 55, false>(tap, frow); break;
    }

    __syncthreads();

    // Flat float4 copy: LDS layout == output layout. Slab base is 16B-aligned;
    // slab spans exactly 462 full 128-B lines.
    // NONTEMPORAL stores: 118 MB streamed output must not write-allocate in
    // the 32 MB aggregate L2 -- write-back eviction thrash throttles the
    // store phase to ~2.5 TB/s while the harness fill hits 6.5 TB/s with the
    // bypass path. `nt` flag = no-allocate / evict-first.
    float* __restrict__ obase = out + ((size_t)row * NT + t0) * NFEAT;
    f32x4* __restrict__ o4 = reinterpret_cast<f32x4*>(obase);
    const f32x4* s4 = reinterpret_cast<const f32x4*>(feat);
    if (tcount == TT) {
        // 64*231/4 = 3696 = 7*512 + 112: unrolled with immediate offsets.
#pragma unroll
        for (int it = 0; it < 7; ++it) {
            const int i = threadIdx.x + it * NTHREADS;
            __builtin_nontemporal_store(s4[i], o4 + i);
        }
        const int i8 = threadIdx.x + 7 * NTHREADS;
        if (i8 < (TT * NFEAT) / 4)
            __builtin_nontemporal_store(s4[i8], o4 + i8);
    } else {
        const int total4 = (tcount * NFEAT) >> 2;    // tail: 28*231/4 = 1617
        for (int i = threadIdx.x; i < total4; i += NTHREADS)
            __builtin_nontemporal_store(s4[i], o4 + i);
    }
}

extern "C" void kernel_launch(void* const* d_in, const int* in_sizes, int n_in,
                              void* d_out, int out_size, void* d_ws, size_t ws_size,
                              hipStream_t stream) {
    const float* X = (const float*)d_in[0];
    float* out = (float*)d_out;
    dim3 grid((NT + TT - 1) / TT, NROWS);        // 63 x 32 = 2016 blocks
    nvar_kernel<<<grid, NTHREADS, 0, stream>>>(X, out);
}

// Round 4
// 120.343 us; speedup vs baseline: 1.0596x; 1.0596x over previous
//
#include <hip/hip_runtime.h>

#define KTAPS 10
#define SKIP  2
#define TRANS 100
#define PAD   ((KTAPS - 1) * SKIP)   // 18
#define NFEAT 231                    // 1 + 10 + 220
#define NIN   4096
#define NT    (NIN - TRANS)          // 3996
#define NROWS 32                     // 8*4
#define TT    64                     // timesteps per block
#define NTHREADS 512                 // 8 waves
#define NTILES ((NT + TT - 1) / TT)  // 63 tiles per row
#define NWG    (NTILES * NROWS)      // 2016 blocks, 2016 % 8 == 0
#define NXCD   8

// Emit monomials for pair-index range [PLO,PHI) of the i<=j pairs (55 total),
// fully unrolled so every f-offset and tap index is a compile-time constant.
// Lex order matches itertools.combinations_with_replacement(range(10), 3).
template<int PLO, int PHI, bool LIN>
__device__ __forceinline__ void emit_features(const float* __restrict__ tap,
                                              float* __restrict__ frow) {
    if (LIN) {
        frow[0] = 1.0f;
#pragma unroll
        for (int k = 0; k < KTAPS; ++k) frow[1 + k] = tap[k];
    }
    int p = 0, fb = 1 + KTAPS;
#pragma unroll
    for (int i = 0; i < KTAPS; ++i) {
#pragma unroll
        for (int j = i; j < KTAPS; ++j) {
            if (p >= PLO && p < PHI) {           // folds: PLO/PHI/p all constants
                const float pij = tap[i] * tap[j];
#pragma unroll
                for (int l = j; l < KTAPS; ++l)
                    frow[fb + (l - j)] = pij * tap[l];
            }
            fb += KTAPS - j;
            ++p;
        }
    }
}

__global__ __launch_bounds__(NTHREADS, 4) void nvar_kernel(const float* __restrict__ X,
                                                           float* __restrict__ out) {
    // LDS tile laid out EXACTLY like the output slab: [t][feat], stride 231.
    // 231 % 32 = 7 (odd, coprime with 32) -> compute-phase writes (fixed f,
    // t = lane 0..63) hit each of the 32 banks exactly twice = free on wave64.
    // 64*231*4 = 59,136 B -> 2 blocks/CU (16 waves/CU).
    __shared__ float feat[TT * NFEAT];

    // XCD-aware swizzle (T1): the dispatcher round-robins linear block ids
    // across the 8 XCDs. Remap so XCD x owns wgid range [x*252,(x+1)*252) =
    // 4 complete output rows = one contiguous 14.8 MB write region per XCD
    // (vs a 59 KB-granular interleave across 8 rows). NWG%8==0 -> simple
    // bijective form is safe (ERRATA #11 doesn't apply).
    const int bid  = blockIdx.x;
    const int wgid = (bid % NXCD) * (NWG / NXCD) + bid / NXCD;
    const int tile = wgid % NTILES;
    const int row  = wgid / NTILES;

    const int t0     = tile * TT;
    const int tcount = min(TT, NT - t0);         // 64, or 28 on the tail tile

    const int tl = threadIdx.x & 63;             // local timestep = full lane id
    const int wq = threadIdx.x >> 6;             // wave id 0..7, wave-uniform

    int tg = t0 + tl;
    if (tg >= NT) tg = NT - 1;                   // tail clamp; extra rows unused

    // lin_k(t) = X[row, t + 82 + 2k]; max index 3995+82+18 = 4095, in-bounds.
    const float* xrow = X + (size_t)row * NIN;
    float tap[KTAPS];
#pragma unroll
    for (int k = 0; k < KTAPS; ++k)
        tap[k] = xrow[tg + (TRANS - PAD) + 2 * k];

    // 8 wave-groups, each covering all 64 timesteps for a disjoint pair-range.
    // Balanced ds_write counts per wave: 30,26,27,28,30,31,29,30.
    float* frow = feat + tl * NFEAT;
    switch (wq) {
        case 0:  emit_features< 0,  2, true >(tap, frow); break;
        case 1:  emit_features< 2,  6, false>(tap, frow); break;
        case 2:  emit_features< 6, 12, false>(tap, frow); break;
        case 3:  emit_features<12, 19, false>(tap, frow); break;
        case 4:  emit_features<19, 24, false>(tap, frow); break;
        case 5:  emit_features<24, 32, false>(tap, frow); break;
        case 6:  emit_features<32, 41, false>(tap, frow); break;
        default: emit_features<41, 55, false>(tap, frow); break;
    }

    __syncthreads();

    // Flat float4 copy: LDS layout == output layout. Slab base is 16B-aligned;
    // slab spans exactly 462 full 128-B lines. Plain (cached) stores: the nt
    // variant measured neutral-to-negative in R3 -- L2 write policy is not
    // the limiter.
    const int total4 = (tcount * NFEAT) >> 2;    // 3696, or 1617 on the tail
    float4* __restrict__ o4 =
        reinterpret_cast<float4*>(out + ((size_t)row * NT + t0) * NFEAT);
    const float4* s4 = reinterpret_cast<const float4*>(feat);
    if (tcount == TT) {
        // 64*231/4 = 3696 = 7*512 + 112: unrolled with immediate offsets.
#pragma unroll
        for (int it = 0; it < 7; ++it) {
            const int i = threadIdx.x + it * NTHREADS;
            o4[i] = s4[i];
        }
        const int i8 = threadIdx.x + 7 * NTHREADS;
        if (i8 < (TT * NFEAT) / 4) o4[i8] = s4[i8];
    } else {
        for (int i = threadIdx.x; i < total4; i += NTHREADS)
            o4[i] = s4[i];
    }
}

extern "C" void kernel_launch(void* const* d_in, const int* in_sizes, int n_in,
                              void* d_out, int out_size, void* d_ws, size_t ws_size,
                              hipStream_t stream) {
    const float* X = (const float*)d_in[0];
    float* out = (float*)d_out;
    nvar_kernel<<<dim3(NWG), NTHREADS, 0, stream>>>(X, out);
}